// Round 7
// baseline (109.169 us; speedup 1.0000x reference)
//
#include <hip/hip_runtime.h>

// VectorQuantizer: split-precision bf16 MFMA (32x32x16, 32 rows/wave),
// LDS double-buffered frag-linear codebook chunks, counted vmcnt.
// z [65536,192] f32, codebook [512,192] f32
// out: z_q [65536*192] f32 ++ indices [65536] (as float)

#define NROWS 65536
#define D     192
#define V     512
#define MARGIN 5e-4f
#define NCHUNK 16                 // V / 32 entries per chunk
#define CHUNK_BYTES 24576         // 32 cols * 192 k * 2B * 2 planes

typedef __attribute__((ext_vector_type(8)))  short short8;   // 8 bf16
typedef __attribute__((ext_vector_type(16))) float f32x16;   // 32x32 C frag

__device__ __forceinline__ unsigned short f2bf(float x) {    // RNE f32->bf16
    unsigned u = __float_as_uint(x);
    u += 0x7FFFu + ((u >> 16) & 1u);
    return (unsigned short)(u >> 16);
}
__device__ __forceinline__ float bf2f(unsigned short h) {
    return __uint_as_float(((unsigned)h) << 16);
}

// ---- prepass: codebook -> frag-linear bf16 hi/lo F + esq ----
// unit u = ((c*12 + s)*2 + p)*64 + lane  (16B per unit)
//   col = c*32 + (lane&31), k = s*16 + (lane>>5)*8 + j
__global__ void vq_prep(const float* __restrict__ cb,
                        short8* __restrict__ F,
                        float* __restrict__ esq) {
    int u = blockIdx.x * 256 + threadIdx.x;        // 0..24575
    int lane = u & 63;
    int t = u >> 6;                                 // (c*12+s)*2+p
    int p = t & 1;
    int t2 = t >> 1;                                // c*12+s
    int c = t2 / 12, s = t2 - c * 12;
    int col  = c * 32 + (lane & 31);
    int koff = s * 16 + (lane >> 5) * 8;
    const float* src = cb + (size_t)col * D + koff;
    float4 a = *(const float4*)(src);
    float4 b = *(const float4*)(src + 4);
    float xs[8] = {a.x, a.y, a.z, a.w, b.x, b.y, b.z, b.w};
    short8 o;
    if (p == 0) {
#pragma unroll
        for (int j = 0; j < 8; ++j) o[j] = (short)f2bf(xs[j]);
    } else {
#pragma unroll
        for (int j = 0; j < 8; ++j) {
            unsigned short hb = f2bf(xs[j]);
            o[j] = (short)f2bf(xs[j] - bf2f(hb));
        }
    }
    F[u] = o;

    if (u < V) {                                    // esq, same order as rescan
        const float4* pp = (const float4*)(cb + (size_t)u * D);
        float4 es = make_float4(0.f, 0.f, 0.f, 0.f);
#pragma unroll
        for (int k = 0; k < D / 4; ++k) {
            float4 e = pp[k];
            es.x = fmaf(e.x, e.x, es.x); es.y = fmaf(e.y, e.y, es.y);
            es.z = fmaf(e.z, e.z, es.z); es.w = fmaf(e.w, e.w, es.w);
        }
        esq[u] = (es.x + es.y) + (es.z + es.w);
    }
}

// ---- exact fp32 rescan (round-1-verified bit-exact formula) ----
__device__ __noinline__ int vq_rescan(const float* __restrict__ z,
                                      const float* __restrict__ cb,
                                      const float* __restrict__ esq,
                                      int row, int lane) {
    const float4* zp = (const float4*)(z + (size_t)row * D);
    float4 s = make_float4(0.f, 0.f, 0.f, 0.f);
    for (int k = 0; k < D / 4; ++k) {
        float4 a = zp[k];
        s.x = fmaf(a.x, a.x, s.x); s.y = fmaf(a.y, a.y, s.y);
        s.z = fmaf(a.z, a.z, s.z); s.w = fmaf(a.w, a.w, s.w);
    }
    float zsq = (s.x + s.y) + (s.z + s.w);
    float bd = 3.402823466e+38f; int bi = V;
    for (int it = 0; it < V / 64; ++it) {
        int e = lane + it * 64;
        const float4* ep = (const float4*)(cb + (size_t)e * D);
        float4 a = make_float4(0.f, 0.f, 0.f, 0.f);
        for (int k = 0; k < D / 4; ++k) {
            float4 b = ep[k], zv = zp[k];
            a.x = fmaf(zv.x, b.x, a.x); a.y = fmaf(zv.y, b.y, a.y);
            a.z = fmaf(zv.z, b.z, a.z); a.w = fmaf(zv.w, b.w, a.w);
        }
        float dot = (a.x + a.y) + (a.z + a.w);
        float d = (zsq + esq[e]) - 2.f * dot;
        if (d < bd) { bd = d; bi = e; }
    }
    for (int m = 1; m < 64; m <<= 1) {
        float od = __shfl_xor(bd, m);
        int   oi = __shfl_xor(bi, m);
        if (od < bd || (od == bd && oi < bi)) { bd = od; bi = oi; }
    }
    return bi;
}

// ------------------------------ main kernel ------------------------------
__global__ __launch_bounds__(256, 2)
void vq_main(const float* __restrict__ z,
             const float* __restrict__ cb,
             const char* __restrict__ F,
             const float* __restrict__ esq,
             float* __restrict__ zq,
             float* __restrict__ idx_out) {
    __shared__ __align__(16) char lds_buf[2][CHUNK_BYTES];
    __shared__ float lds_esq[V];

    const int tid  = threadIdx.x;
    const int wave = tid >> 6;
    const int lane = tid & 63;
    const int l31  = lane & 31;
    const int half = lane >> 5;

    const int rowbase = blockIdx.x * 128 + wave * 32;
    const int myrow   = rowbase + l31;

    // esq -> LDS (first 128 threads)
    if (tid < 128)
        ((float4*)lds_esq)[tid] = ((const float4*)esq)[tid];

    // ---- A prologue: z row -> 12 k-step hi/lo frags ----
    short8 zhi[12], zlo[12];
    {
        const float* zr = z + (size_t)myrow * D + half * 8;
#pragma unroll
        for (int s = 0; s < 12; ++s) {
            float4 a = *(const float4*)(zr + s * 16);
            float4 b = *(const float4*)(zr + s * 16 + 4);
            float xs[8] = {a.x, a.y, a.z, a.w, b.x, b.y, b.z, b.w};
            short8 h, l;
#pragma unroll
            for (int j = 0; j < 8; ++j) {
                unsigned short hb = f2bf(xs[j]);
                h[j] = (short)hb;
                l[j] = (short)f2bf(xs[j] - bf2f(hb));
            }
            zhi[s] = h; zlo[s] = l;
        }
    }

    float v1q[16], v2q[16]; int i1q[16];
#pragma unroll
    for (int q = 0; q < 16; ++q) { v1q[q] = 3.402823466e+38f; v2q[q] = 3.402823466e+38f; i1q[q] = 0; }

#define STAGE(CC, BUF)                                                          \
    {                                                                           \
        const char* gsrc = F + (size_t)(CC) * CHUNK_BYTES + wave * 6144 + lane * 16; \
        char* ldst = &lds_buf[BUF][0] + wave * 6144;                            \
        _Pragma("unroll")                                                       \
        for (int it = 0; it < 6; ++it)                                          \
            __builtin_amdgcn_global_load_lds(                                   \
                (const __attribute__((address_space(1))) void*)(gsrc + it * 1024), \
                (__attribute__((address_space(3))) void*)(ldst + it * 1024),    \
                16, 0, 0);                                                      \
    }

    STAGE(0, 0);
    asm volatile("s_waitcnt lgkmcnt(0)" ::: "memory");   // esq ds_write drained

    for (int c = 0; c < NCHUNK; ++c) {
        const int cur = c & 1;
        if (c + 1 < NCHUNK) {
            STAGE(c + 1, cur ^ 1);                       // prefetch next chunk
            asm volatile("s_waitcnt vmcnt(6)" ::: "memory");  // chunk c staged
        } else {
            asm volatile("s_waitcnt vmcnt(0)" ::: "memory");
        }
        __builtin_amdgcn_s_barrier();                    // A: buf[cur] ready

        const char* B = &lds_buf[cur][0];
        f32x16 accA, accB, accC;
#pragma unroll
        for (int q = 0; q < 16; ++q) { accA[q] = 0.f; accB[q] = 0.f; accC[q] = 0.f; }

        __builtin_amdgcn_s_setprio(1);
#pragma unroll
        for (int s = 0; s < 12; ++s) {
            short8 bh = *(const short8*)(B + (s * 2 + 0) * 1024 + lane * 16);
            short8 bl = *(const short8*)(B + (s * 2 + 1) * 1024 + lane * 16);
            accA = __builtin_amdgcn_mfma_f32_32x32x16_bf16(zhi[s], bh, accA, 0, 0, 0);
            accB = __builtin_amdgcn_mfma_f32_32x32x16_bf16(zlo[s], bh, accB, 0, 0, 0);
            accC = __builtin_amdgcn_mfma_f32_32x32x16_bf16(zhi[s], bl, accC, 0, 0, 0);
        }
        __builtin_amdgcn_s_setprio(0);

        asm volatile("s_waitcnt lgkmcnt(0)" ::: "memory");
        __builtin_amdgcn_s_barrier();                    // B: reads of buf[cur] done

        const float e  = lds_esq[c * 32 + l31];
        const int  idx = c * 32 + l31;
#pragma unroll
        for (int q = 0; q < 16; ++q) {
            float dot = (accA[q] + accB[q]) + accC[q];
            float d = fmaf(-2.f, dot, e);
            bool b = d < v1q[q];
            v2q[q] = fminf(b ? v1q[q] : d, v2q[q]);
            i1q[q] = b ? idx : i1q[q];
            v1q[q] = b ? d : v1q[q];
        }
    }
#undef STAGE

    // ---- cross-lane top2 merge within each 32-lane half ----
#pragma unroll
    for (int q = 0; q < 16; ++q) {
#pragma unroll
        for (int m = 1; m <= 16; m <<= 1) {
            float ov1 = __shfl_xor(v1q[q], m);
            int   oi1 = __shfl_xor(i1q[q], m);
            float ov2 = __shfl_xor(v2q[q], m);
            bool take = (ov1 < v1q[q]) || ((ov1 == v1q[q]) && (oi1 < i1q[q]));
            float lose = take ? v1q[q] : ov1;
            v2q[q] = fminf(fminf(v2q[q], ov2), lose);
            v1q[q] = take ? ov1 : v1q[q];
            i1q[q] = take ? oi1 : i1q[q];
        }
    }

    // ---- epilogue: rare exact rescan + wave-cooperative gather + idx ----
#pragma unroll
    for (int q = 0; q < 16; ++q) {
        bool nd = (v2q[q] - v1q[q]) <= MARGIN;
        unsigned long long bm = __ballot(nd);
        int idx = i1q[q];
        const int r0 = rowbase + (q & 3) + 8 * (q >> 2);
        if (bm & 1ull) {                      // half 0 ambiguous (uniform)
            int ridx = vq_rescan(z, cb, esq, r0, lane);
            if (half == 0) idx = ridx;
        }
        if ((bm >> 32) & 1ull) {              // half 1 ambiguous (uniform)
            int ridx = vq_rescan(z, cb, esq, r0 + 4, lane);
            if (half == 1) idx = ridx;
        }
        const int row = r0 + half * 4;
        const float4* srcv = (const float4*)(cb + (size_t)idx * D);
        float4* dstv = (float4*)(zq + (size_t)row * D);
        dstv[l31] = srcv[l31];
        if (l31 < 16) dstv[32 + l31] = srcv[32 + l31];
        if (l31 == 0) idx_out[row] = (float)idx;
    }
}

// --------- round-1 fallback (only if ws is unexpectedly small) ---------
#define TV 32
#define FBLOCK 128
__global__ __launch_bounds__(FBLOCK, 2)
void vq_argmin_fallback(const float* __restrict__ z, const float* __restrict__ cb,
                        float* __restrict__ zq, float* __restrict__ idx_out) {
    __shared__ float lds_cb[TV * D];
    __shared__ float lds_esq2[TV];
    const int row = blockIdx.x * FBLOCK + threadIdx.x;
    float4 zr[D / 4];
    const float4* zp = (const float4*)(z + (size_t)row * D);
    float4 s = make_float4(0.f, 0.f, 0.f, 0.f);
#pragma unroll
    for (int i = 0; i < D / 4; ++i) {
        zr[i] = zp[i];
        s.x = fmaf(zr[i].x, zr[i].x, s.x); s.y = fmaf(zr[i].y, zr[i].y, s.y);
        s.z = fmaf(zr[i].z, zr[i].z, s.z); s.w = fmaf(zr[i].w, zr[i].w, s.w);
    }
    const float zsq = (s.x + s.y) + (s.z + s.w);
    float best = 3.4e38f; int bidx = 0;
    for (int vt = 0; vt < V / TV; ++vt) {
        __syncthreads();
        const float4* cbp = (const float4*)(cb + (size_t)vt * TV * D);
        float4* l4 = (float4*)lds_cb;
#pragma unroll
        for (int i = 0; i < (TV * D / 4) / FBLOCK; ++i)
            l4[threadIdx.x + i * FBLOCK] = cbp[threadIdx.x + i * FBLOCK];
        __syncthreads();
        if (threadIdx.x < TV) {
            const float* e = lds_cb + threadIdx.x * D;
            float4 es = make_float4(0.f, 0.f, 0.f, 0.f);
#pragma unroll
            for (int k = 0; k < D; k += 4) {
                es.x = fmaf(e[k], e[k], es.x); es.y = fmaf(e[k+1], e[k+1], es.y);
                es.z = fmaf(e[k+2], e[k+2], es.z); es.w = fmaf(e[k+3], e[k+3], es.w);
            }
            lds_esq2[threadIdx.x] = (es.x + es.y) + (es.z + es.w);
        }
        __syncthreads();
#pragma unroll 2
        for (int v = 0; v < TV; ++v) {
            const float4* e4 = (const float4*)(lds_cb + v * D);
            float4 a = make_float4(0.f, 0.f, 0.f, 0.f);
#pragma unroll
            for (int k = 0; k < D / 4; ++k) {
                float4 b = e4[k];
                a.x = fmaf(zr[k].x, b.x, a.x); a.y = fmaf(zr[k].y, b.y, a.y);
                a.z = fmaf(zr[k].z, b.z, a.z); a.w = fmaf(zr[k].w, b.w, a.w);
            }
            const float dot = (a.x + a.y) + (a.z + a.w);
            const float dist = (zsq + lds_esq2[v]) - 2.f * dot;
            if (dist < best) { best = dist; bidx = vt * TV + v; }
        }
    }
    float4* zqp = (float4*)(zq + (size_t)row * D);
    const float4* bp = (const float4*)(cb + (size_t)bidx * D);
#pragma unroll
    for (int i = 0; i < D / 4; ++i) zqp[i] = bp[i];
    idx_out[row] = (float)bidx;
}

extern "C" void kernel_launch(void* const* d_in, const int* in_sizes, int n_in,
                              void* d_out, int out_size, void* d_ws, size_t ws_size,
                              hipStream_t stream) {
    const float* z  = (const float*)d_in[0];
    const float* cb = (const float*)d_in[1];
    float* zq      = (float*)d_out;
    float* idx_out = (float*)d_out + (size_t)NROWS * D;

    const size_t f_bytes = (size_t)NCHUNK * CHUNK_BYTES;    // 393216
    const size_t need = f_bytes + V * sizeof(float);
    if (ws_size < need) {
        vq_argmin_fallback<<<NROWS / FBLOCK, FBLOCK, 0, stream>>>(z, cb, zq, idx_out);
        return;
    }
    short8* F  = (short8*)d_ws;
    float* esq = (float*)((char*)d_ws + f_bytes);

    vq_prep<<<96, 256, 0, stream>>>(cb, F, esq);
    vq_main<<<NROWS / 128, 256, 0, stream>>>(z, cb, (const char*)F, esq, zq, idx_out);
}